// Round 5
// baseline (128.452 us; speedup 1.0000x reference)
//
#include <hip/hip_runtime.h>
#include <hip/hip_bf16.h>

#define B_ 16
#define T_ 2048
#define C_ 1024
#define HD_ 64

typedef __attribute__((ext_vector_type(8))) short bf16x8;
typedef __attribute__((ext_vector_type(4))) float f32x4;

__device__ __forceinline__ unsigned short f2bf(float f) {
  return __builtin_bit_cast(unsigned short, __float2bfloat16(f));
}

__device__ __forceinline__ bf16x8 cvt8(float4 a, float4 b) {
  bf16x8 r;
  r[0] = (short)f2bf(a.x); r[1] = (short)f2bf(a.y);
  r[2] = (short)f2bf(a.z); r[3] = (short)f2bf(a.w);
  r[4] = (short)f2bf(b.x); r[5] = (short)f2bf(b.y);
  r[6] = (short)f2bf(b.z); r[7] = (short)f2bf(b.w);
  return r;
}

// ---- W convert to MFMA B-fragment layout ----
// wfrag[((kk*24 + f)*64 + lane)*8 + e], kk=0..15 (K-step of 64), f = ks*12 + cf,
// lane = lh*16 + l15:  value = Wfold[r][k],  r = (cf>>2)*64 + (cf&3)*16 + l15,
// k = kk*64 + ks*32 + lh*8 + e.  Wfold[r][k] = W_m[k][d]*scale, m=r>>6, d=r&63.
// scale: 1/sqrt(C) * log2(e) folded into Wk (m==0) -> scores in exp2 domain.
__global__ void wconv_kernel(const float* __restrict__ Wk, const float* __restrict__ Wq,
                             const float* __restrict__ Wv, unsigned short* __restrict__ wfrag) {
  int o = blockIdx.x * 256 + threadIdx.x;   // 16*24*64*8 = 196608 total
  if (o >= 16 * 24 * 64 * 8) return;
  int e = o & 7;
  int lane = (o >> 3) & 63;
  int t = o >> 9;              // kk*24 + f
  int kk = t / 24;
  int f = t % 24;
  int ks = f / 12;
  int cf = f % 12;
  int l15 = lane & 15, lh = lane >> 4;
  int m = cf >> 2;
  int d = (cf & 3) * 16 + l15;
  int k = kk * 64 + ks * 32 + lh * 8 + e;
  const float* W = (m == 0) ? Wk : (m == 1) ? Wq : Wv;
  float v = W[k * HD_ + d];
  if (m == 0) v *= 0.03125f * 1.44269504088896f;
  wfrag[o] = f2bf(v);
}

// ---------------- QKV projection v4: barrier-free, register-pipelined ----------------
// 512 blocks x 256 threads (4 independent waves). 16 rows/wave, all 192 cols.
// W fragments: contiguous 1KB wave-loads from wfrag (L1/L2-hot), 3-slot rolling
// register window, prefetch depth 2 groups. x: global->reg, depth-1 K-step prefetch.
// No LDS, no __syncthreads — waves free-run; compiler inserts counted waits.
__global__ __launch_bounds__(256, 2) void qkv_kernel(const float* __restrict__ x,
                                                     const unsigned short* __restrict__ wfrag,
                                                     unsigned short* __restrict__ kb,
                                                     unsigned short* __restrict__ qb,
                                                     unsigned short* __restrict__ vb) {
  const int tid = threadIdx.x;
  const int lane = tid & 63;
  const int w = tid >> 6;
  const int l15 = lane & 15;
  const int lh = lane >> 4;
  const int r0 = blockIdx.x * 64;

  const float* xp = x + (size_t)(r0 + w * 16 + l15) * C_ + lh * 8;
  const unsigned short* wp = wfrag + lane * 8;

  f32x4 acc[12];
#pragma unroll
  for (int i = 0; i < 12; ++i) acc[i] = {0.f, 0.f, 0.f, 0.f};

  float4 xr[2][4];
  bf16x8 wg[3][4];

#define WLOAD(SLOT, GQ)                                                        \
  do {                                                                         \
    _Pragma("unroll")                                                          \
    for (int i_ = 0; i_ < 4; ++i_)                                             \
      wg[SLOT][i_] = *(const bf16x8*)(wp + ((GQ) * 4 + i_) * 512);             \
  } while (0)

#define XLOAD(SLOT, KK)                                 \
  do {                                                  \
    const float* p_ = xp + (KK) * 64;                   \
    xr[SLOT][0] = *(const float4*)(p_);                 \
    xr[SLOT][1] = *(const float4*)(p_ + 4);             \
    xr[SLOT][2] = *(const float4*)(p_ + 32);            \
    xr[SLOT][3] = *(const float4*)(p_ + 36);            \
  } while (0)

  // prologue
  XLOAD(0, 0);
  WLOAD(0, 0);
  WLOAD(1, 1);

#pragma unroll
  for (int kk = 0; kk < 16; ++kk) {
    if (kk < 15) XLOAD((kk + 1) & 1, kk + 1);
    bf16x8 a0 = cvt8(xr[kk & 1][0], xr[kk & 1][1]);
    bf16x8 a1 = cvt8(xr[kk & 1][2], xr[kk & 1][3]);
#pragma unroll
    for (int g = 0; g < 6; ++g) {
      const int GQ = kk * 6 + g;
      if (GQ + 2 <= 95) WLOAD((GQ + 2) % 3, GQ + 2);
#pragma unroll
      for (int i = 0; i < 4; ++i) {
        const int f = g * 4 + i;
        const int cf = f % 12;
        if (f < 12)
          acc[cf] = __builtin_amdgcn_mfma_f32_16x16x32_bf16(a0, wg[GQ % 3][i], acc[cf], 0, 0, 0);
        else
          acc[cf] = __builtin_amdgcn_mfma_f32_16x16x32_bf16(a1, wg[GQ % 3][i], acc[cf], 0, 0, 0);
      }
    }
  }
#undef WLOAD
#undef XLOAD

  // epilogue: C/D layout col=lane&15, row=(lane>>4)*4+r (scales pre-folded in wconv)
#pragma unroll
  for (int cf = 0; cf < 4; ++cf) {
    int col = cf * 16 + l15;
#pragma unroll
    for (int r = 0; r < 4; ++r) {
      size_t row = (size_t)(r0 + w * 16 + lh * 4 + r);
      kb[row * HD_ + col] = f2bf(acc[cf][r]);
      qb[row * HD_ + col] = f2bf(acc[4 + cf][r]);
      vb[row * HD_ + col] = f2bf(acc[8 + cf][r]);
    }
  }
}

// ---------------- flash attention v2 (unchanged from round 4) ----------------
__global__ __launch_bounds__(256) void attn_kernel(const unsigned short* __restrict__ kb,
                                                   const unsigned short* __restrict__ qb,
                                                   const unsigned short* __restrict__ vb,
                                                   float* __restrict__ out) {
  __shared__ __align__(16) unsigned short q_lds[2][64 * 72];  // [s][d] padded
  __shared__ __align__(16) unsigned short v_lds[2][64 * 72];  // [d][s] padded (transposed)
  __shared__ __align__(16) unsigned short p_lds[64 * 72];     // [t][s] padded (same-wave only)

  const int tid = threadIdx.x;
  const int lane = tid & 63;
  const int w = tid >> 6;
  const int bid = blockIdx.x;
  const int idx = bid >> 4;
  const int jt = (idx < 16) ? (31 - idx) : (idx - 16);
  const int b = bid & 15;
  const int t0 = jt * 64;
  const int l15 = lane & 15;
  const int lh = lane >> 4;
  const size_t base = (size_t)b * T_ * HD_;

  const int qrow = tid >> 3, qc8 = tid & 7;
  const int vss = tid & 63, vd0 = (tid >> 6) * 8;

  bf16x8 kf[2];
#pragma unroll
  for (int ks = 0; ks < 2; ++ks)
    kf[ks] = *reinterpret_cast<const bf16x8*>(
        &kb[base + (size_t)(t0 + w * 16 + l15) * HD_ + ks * 32 + lh * 8]);

  bf16x8 qr0, qr1, vr0, vr1;
  qr0 = *reinterpret_cast<const bf16x8*>(&qb[base + (size_t)qrow * HD_ + qc8 * 8]);
  qr1 = *reinterpret_cast<const bf16x8*>(&qb[base + (size_t)(qrow + 32) * HD_ + qc8 * 8]);
  vr0 = *reinterpret_cast<const bf16x8*>(&vb[base + (size_t)vss * HD_ + vd0]);
  vr1 = *reinterpret_cast<const bf16x8*>(&vb[base + (size_t)vss * HD_ + vd0 + 32]);

  f32x4 o[4];
#pragma unroll
  for (int i = 0; i < 4; ++i) o[i] = {0.f, 0.f, 0.f, 0.f};
  float mrun[4], lrun[4];
#pragma unroll
  for (int r = 0; r < 4; ++r) { mrun[r] = -1e30f; lrun[r] = 0.f; }

  for (int j = 0; j <= jt; ++j) {
    const int buf = j & 1;
    *reinterpret_cast<bf16x8*>(&q_lds[buf][qrow * 72 + qc8 * 8]) = qr0;
    *reinterpret_cast<bf16x8*>(&q_lds[buf][(qrow + 32) * 72 + qc8 * 8]) = qr1;
#pragma unroll
    for (int jj = 0; jj < 8; ++jj) v_lds[buf][(vd0 + jj) * 72 + vss] = (unsigned short)vr0[jj];
#pragma unroll
    for (int jj = 0; jj < 8; ++jj) v_lds[buf][(vd0 + 32 + jj) * 72 + vss] = (unsigned short)vr1[jj];
    __syncthreads();

    if (j < jt) {
      const size_t sb = base + (size_t)(j + 1) * 64 * HD_;
      qr0 = *reinterpret_cast<const bf16x8*>(&qb[sb + (size_t)qrow * HD_ + qc8 * 8]);
      qr1 = *reinterpret_cast<const bf16x8*>(&qb[sb + (size_t)(qrow + 32) * HD_ + qc8 * 8]);
      vr0 = *reinterpret_cast<const bf16x8*>(&vb[sb + (size_t)vss * HD_ + vd0]);
      vr1 = *reinterpret_cast<const bf16x8*>(&vb[sb + (size_t)vss * HD_ + vd0 + 32]);
    }
    __builtin_amdgcn_sched_barrier(0);

    f32x4 sf[4];
#pragma unroll
    for (int cf = 0; cf < 4; ++cf) sf[cf] = {0.f, 0.f, 0.f, 0.f};
    __builtin_amdgcn_s_setprio(1);
#pragma unroll
    for (int ks = 0; ks < 2; ++ks) {
#pragma unroll
      for (int cf = 0; cf < 4; ++cf) {
        bf16x8 bq = *reinterpret_cast<const bf16x8*>(&q_lds[buf][(cf * 16 + l15) * 72 + ks * 32 + lh * 8]);
        sf[cf] = __builtin_amdgcn_mfma_f32_16x16x32_bf16(kf[ks], bq, sf[cf], 0, 0, 0);
      }
    }
    __builtin_amdgcn_s_setprio(0);

    const bool diag = (j == jt);
    const int s0 = j * 64;
    float pv[4][4];
#pragma unroll
    for (int r = 0; r < 4; ++r) {
      const int tg = t0 + w * 16 + lh * 4 + r;
      float pm = -1e30f;
#pragma unroll
      for (int cf = 0; cf < 4; ++cf) {
        float v = sf[cf][r];
        if (diag && (s0 + cf * 16 + l15) > tg) v = -1e30f;
        pv[cf][r] = v;
        pm = fmaxf(pm, v);
      }
      pm = fmaxf(pm, __shfl_xor(pm, 1));
      pm = fmaxf(pm, __shfl_xor(pm, 2));
      pm = fmaxf(pm, __shfl_xor(pm, 4));
      pm = fmaxf(pm, __shfl_xor(pm, 8));
      float mn = fmaxf(mrun[r], pm);
      float scl = exp2f(mrun[r] - mn);
      mrun[r] = mn;
      float rs = 0.f;
#pragma unroll
      for (int cf = 0; cf < 4; ++cf) {
        float e = exp2f(pv[cf][r] - mn);
        pv[cf][r] = e;
        rs += e;
      }
      rs += __shfl_xor(rs, 1);
      rs += __shfl_xor(rs, 2);
      rs += __shfl_xor(rs, 4);
      rs += __shfl_xor(rs, 8);
      lrun[r] = lrun[r] * scl + rs;
#pragma unroll
      for (int df = 0; df < 4; ++df) o[df][r] *= scl;
    }
#pragma unroll
    for (int cf = 0; cf < 4; ++cf)
#pragma unroll
      for (int r = 0; r < 4; ++r)
        p_lds[(w * 16 + lh * 4 + r) * 72 + cf * 16 + l15] = f2bf(pv[cf][r]);

    __builtin_amdgcn_s_setprio(1);
#pragma unroll
    for (int ks = 0; ks < 2; ++ks) {
      bf16x8 pa = *reinterpret_cast<const bf16x8*>(&p_lds[(w * 16 + l15) * 72 + ks * 32 + lh * 8]);
#pragma unroll
      for (int df = 0; df < 4; ++df) {
        bf16x8 bv = *reinterpret_cast<const bf16x8*>(&v_lds[buf][(df * 16 + l15) * 72 + ks * 32 + lh * 8]);
        o[df] = __builtin_amdgcn_mfma_f32_16x16x32_bf16(pa, bv, o[df], 0, 0, 0);
      }
    }
    __builtin_amdgcn_s_setprio(0);
  }

#pragma unroll
  for (int r = 0; r < 4; ++r) {
    float inv = 1.f / lrun[r];
    int row = t0 + w * 16 + lh * 4 + r;
#pragma unroll
    for (int df = 0; df < 4; ++df)
      out[base + (size_t)row * HD_ + df * 16 + l15] = o[df][r] * inv;
  }
}

extern "C" void kernel_launch(void* const* d_in, const int* in_sizes, int n_in,
                              void* d_out, int out_size, void* d_ws, size_t ws_size,
                              hipStream_t stream) {
  const float* x  = (const float*)d_in[0];
  const float* Wk = (const float*)d_in[1];
  const float* Wq = (const float*)d_in[2];
  const float* Wv = (const float*)d_in[3];
  float* out = (float*)d_out;

  char* ws = (char*)d_ws;
  unsigned short* wfrag = (unsigned short*)ws;                               // 384 KB
  unsigned short* kb = (unsigned short*)(ws + 524288);                       // 4 MB
  unsigned short* qb = (unsigned short*)(ws + 524288 + 4 * 1024 * 1024);     // 4 MB
  unsigned short* vb = (unsigned short*)(ws + 524288 + 8 * 1024 * 1024);     // 4 MB

  hipLaunchKernelGGL(wconv_kernel, dim3(768), dim3(256), 0, stream, Wk, Wq, Wv, wfrag);
  hipLaunchKernelGGL(qkv_kernel, dim3(512), dim3(256), 0, stream, x, wfrag, kb, qb, vb);
  hipLaunchKernelGGL(attn_kernel, dim3(512), dim3(256), 0, stream, kb, qb, vb, out);
}

// Round 6
// 112.560 us; speedup vs baseline: 1.1412x; 1.1412x over previous
//
#include <hip/hip_runtime.h>
#include <hip/hip_bf16.h>

#define B_ 16
#define T_ 2048
#define C_ 1024
#define HD_ 64

typedef __attribute__((ext_vector_type(8))) short bf16x8;
typedef __attribute__((ext_vector_type(4))) float f32x4;

__device__ __forceinline__ unsigned short f2bf(float f) {
  return __builtin_bit_cast(unsigned short, __float2bfloat16(f));
}

__device__ __forceinline__ bf16x8 cvt8(float4 a, float4 b) {
  bf16x8 r;
  r[0] = (short)f2bf(a.x); r[1] = (short)f2bf(a.y);
  r[2] = (short)f2bf(a.z); r[3] = (short)f2bf(a.w);
  r[4] = (short)f2bf(b.x); r[5] = (short)f2bf(b.y);
  r[6] = (short)f2bf(b.z); r[7] = (short)f2bf(b.w);
  return r;
}

// ---- W convert: per-K-step tiles w3[kk][n], n = element within 24KB tile ----
// LDS byte A = n*2: row = A>>7 (192 rows, 128B lines), chunk c = (A>>4)&7, e = (A>>1)&7.
// Logical: k = kk*64 + ((c ^ (row&7))*8 + e); col row: m = row>>6, d = row&63.
// Scale 1/sqrt(C)*log2(e) folded into Wk (m==0) -> scores in exp2 domain.
__global__ void wconv_kernel(const float* __restrict__ Wk, const float* __restrict__ Wq,
                             const float* __restrict__ Wv, unsigned short* __restrict__ w3) {
  int o = blockIdx.x * 256 + threadIdx.x;   // 16*12288 = 196608 total
  if (o >= 16 * 12288) return;
  int kk = o / 12288;
  int n = o - kk * 12288;
  int row = n >> 6;
  int c = (n >> 3) & 7;
  int e = n & 7;
  int k = kk * 64 + (((c ^ (row & 7)) << 3) | e);
  int m = row >> 6, d = row & 63;
  const float* W = (m == 0) ? Wk : (m == 1) ? Wq : Wv;
  float v = W[k * HD_ + d];
  if (m == 0) v *= 0.03125f * 1.44269504088896f;
  w3[o] = f2bf(v);
}

// ---------------- QKV projection v5: rolled, col-split, 12 waves/CU ----------------
// 1024 blocks x 256 threads (4 waves). Block: 32 rows x 192 cols.
// Wave (rh,ch): rows rh*16, cols ch*96 (6 col-frags). 12 MFMA + 12 ds_read/step.
// W: 24KB/step LDS dbuf via global_load_lds; counted vmcnt(10); rolled loop (x2 ping-pong).
__global__ __launch_bounds__(256, 3) void qkv_kernel(const float* __restrict__ x,
                                                     const unsigned short* __restrict__ w3,
                                                     unsigned short* __restrict__ kb,
                                                     unsigned short* __restrict__ qb,
                                                     unsigned short* __restrict__ vb) {
  __shared__ __align__(16) unsigned short wl[2 * 12288];   // 2 x 24576 B

  const int tid = threadIdx.x;
  const int lane = tid & 63;
  const int w = tid >> 6;
  const int rh = w >> 1, ch = w & 1;
  const int l15 = lane & 15, lh = lane >> 4;
  const int r0 = blockIdx.x * 32;

  const float* xq = x + (size_t)(r0 + rh * 16 + l15) * C_ + lh * 8;
  // frag read element offsets (row stride 64 elem = 128 B, chunk^(l15&7) swizzle)
  const int fb0 = (ch * 96 + l15) * 64 + ((lh ^ (l15 & 7)) << 3);
  const int fb1 = (ch * 96 + l15) * 64 + (((4 | lh) ^ (l15 & 7)) << 3);

  f32x4 acc[6];
#pragma unroll
  for (int i = 0; i < 6; ++i) acc[i] = {0.f, 0.f, 0.f, 0.f};

  float4 xa0, xa1, xa2, xa3, xb0, xb1, xb2, xb3;

#define STAGE(BUF, WS)                                                              \
  do {                                                                              \
    _Pragma("unroll")                                                               \
    for (int i_ = 0; i_ < 6; ++i_) {                                                \
      const int idx_ = i_ * 256 + tid;                                              \
      __builtin_amdgcn_global_load_lds(                                             \
          (const __attribute__((address_space(1))) void*)((WS) + idx_ * 8),         \
          (__attribute__((address_space(3))) void*)&wl[(BUF) * 12288 + idx_ * 8],   \
          16, 0, 0);                                                                \
    }                                                                               \
  } while (0)

#define XLOADA(P) do { const float* p_ = (P);                                  \
    xa0 = *(const float4*)(p_);      xa1 = *(const float4*)(p_ + 4);           \
    xa2 = *(const float4*)(p_ + 32); xa3 = *(const float4*)(p_ + 36); } while (0)
#define XLOADB(P) do { const float* p_ = (P);                                  \
    xb0 = *(const float4*)(p_);      xb1 = *(const float4*)(p_ + 4);           \
    xb2 = *(const float4*)(p_ + 32); xb3 = *(const float4*)(p_ + 36); } while (0)

#define COMPUTE(BUF, X0, X1, X2, X3)                                                \
  do {                                                                              \
    bf16x8 a0 = cvt8(X0, X1);                                                       \
    bf16x8 a1 = cvt8(X2, X3);                                                       \
    _Pragma("unroll")                                                               \
    for (int f_ = 0; f_ < 6; ++f_) {                                                \
      bf16x8 b0 = *(const bf16x8*)&wl[(BUF) * 12288 + f_ * 1024 + fb0];             \
      acc[f_] = __builtin_amdgcn_mfma_f32_16x16x32_bf16(a0, b0, acc[f_], 0, 0, 0);  \
      bf16x8 b1 = *(const bf16x8*)&wl[(BUF) * 12288 + f_ * 1024 + fb1];             \
      acc[f_] = __builtin_amdgcn_mfma_f32_16x16x32_bf16(a1, b1, acc[f_], 0, 0, 0);  \
    }                                                                               \
  } while (0)

#define SB __builtin_amdgcn_sched_barrier(0)
#define WAIT(VM)                                                  \
  do {                                                            \
    SB;                                                           \
    asm volatile("s_waitcnt vmcnt(" #VM ")" ::: "memory");        \
    SB;                                                           \
    __builtin_amdgcn_s_barrier();                                 \
  } while (0)

  const unsigned short* ws = w3;
  // prologue: stage kk=0 -> buf0, load x(0)
  STAGE(0, ws);
  ws += 12288;
  XLOADA(xq);

#pragma unroll 1
  for (int it = 0; it < 7; ++it) {
    // body A: kk even — compute buf0/xa, stage kk+1 -> buf1, prefetch x(kk+1)
    STAGE(1, ws);
    ws += 12288;
    XLOADB(xq + 64);
    WAIT(10);
    COMPUTE(0, xa0, xa1, xa2, xa3);
    __builtin_amdgcn_s_barrier();
    // body B: kk odd — compute buf1/xb, stage kk+2 -> buf0, prefetch x(kk+2)
    STAGE(0, ws);
    ws += 12288;
    XLOADA(xq + 128);
    WAIT(10);
    COMPUTE(1, xb0, xb1, xb2, xb3);
    __builtin_amdgcn_s_barrier();
    xq += 128;
  }
  // peeled kk=14
  STAGE(1, ws);
  XLOADB(xq + 64);
  WAIT(10);
  COMPUTE(0, xa0, xa1, xa2, xa3);
  __builtin_amdgcn_s_barrier();
  // peeled kk=15
  WAIT(0);
  COMPUTE(1, xb0, xb1, xb2, xb3);

#undef WAIT
#undef SB
#undef COMPUTE
#undef XLOADB
#undef XLOADA
#undef STAGE

  // epilogue: C/D layout col=lane&15, row=(lane>>4)*4+r; col-half mapping
#pragma unroll
  for (int rr = 0; rr < 4; ++rr) {
    size_t row = (size_t)(r0 + rh * 16 + lh * 4 + rr);
    if (ch == 0) {
#pragma unroll
      for (int f = 0; f < 4; ++f)
        kb[row * HD_ + f * 16 + l15] = f2bf(acc[f][rr]);
      qb[row * HD_ + 0 + l15]  = f2bf(acc[4][rr]);
      qb[row * HD_ + 16 + l15] = f2bf(acc[5][rr]);
    } else {
      qb[row * HD_ + 32 + l15] = f2bf(acc[0][rr]);
      qb[row * HD_ + 48 + l15] = f2bf(acc[1][rr]);
#pragma unroll
      for (int f = 2; f < 6; ++f)
        vb[row * HD_ + (f - 2) * 16 + l15] = f2bf(acc[f][rr]);
    }
  }
}

// ---------------- flash attention v2 (unchanged from round 4) ----------------
__global__ __launch_bounds__(256) void attn_kernel(const unsigned short* __restrict__ kb,
                                                   const unsigned short* __restrict__ qb,
                                                   const unsigned short* __restrict__ vb,
                                                   float* __restrict__ out) {
  __shared__ __align__(16) unsigned short q_lds[2][64 * 72];
  __shared__ __align__(16) unsigned short v_lds[2][64 * 72];
  __shared__ __align__(16) unsigned short p_lds[64 * 72];

  const int tid = threadIdx.x;
  const int lane = tid & 63;
  const int w = tid >> 6;
  const int bid = blockIdx.x;
  const int idx = bid >> 4;
  const int jt = (idx < 16) ? (31 - idx) : (idx - 16);
  const int b = bid & 15;
  const int t0 = jt * 64;
  const int l15 = lane & 15;
  const int lh = lane >> 4;
  const size_t base = (size_t)b * T_ * HD_;

  const int qrow = tid >> 3, qc8 = tid & 7;
  const int vss = tid & 63, vd0 = (tid >> 6) * 8;

  bf16x8 kf[2];
#pragma unroll
  for (int ks = 0; ks < 2; ++ks)
    kf[ks] = *reinterpret_cast<const bf16x8*>(
        &kb[base + (size_t)(t0 + w * 16 + l15) * HD_ + ks * 32 + lh * 8]);

  bf16x8 qr0, qr1, vr0, vr1;
  qr0 = *reinterpret_cast<const bf16x8*>(&qb[base + (size_t)qrow * HD_ + qc8 * 8]);
  qr1 = *reinterpret_cast<const bf16x8*>(&qb[base + (size_t)(qrow + 32) * HD_ + qc8 * 8]);
  vr0 = *reinterpret_cast<const bf16x8*>(&vb[base + (size_t)vss * HD_ + vd0]);
  vr1 = *reinterpret_cast<const bf16x8*>(&vb[base + (size_t)vss * HD_ + vd0 + 32]);

  f32x4 o[4];
#pragma unroll
  for (int i = 0; i < 4; ++i) o[i] = {0.f, 0.f, 0.f, 0.f};
  float mrun[4], lrun[4];
#pragma unroll
  for (int r = 0; r < 4; ++r) { mrun[r] = -1e30f; lrun[r] = 0.f; }

  for (int j = 0; j <= jt; ++j) {
    const int buf = j & 1;
    *reinterpret_cast<bf16x8*>(&q_lds[buf][qrow * 72 + qc8 * 8]) = qr0;
    *reinterpret_cast<bf16x8*>(&q_lds[buf][(qrow + 32) * 72 + qc8 * 8]) = qr1;
#pragma unroll
    for (int jj = 0; jj < 8; ++jj) v_lds[buf][(vd0 + jj) * 72 + vss] = (unsigned short)vr0[jj];
#pragma unroll
    for (int jj = 0; jj < 8; ++jj) v_lds[buf][(vd0 + 32 + jj) * 72 + vss] = (unsigned short)vr1[jj];
    __syncthreads();

    if (j < jt) {
      const size_t sb = base + (size_t)(j + 1) * 64 * HD_;
      qr0 = *reinterpret_cast<const bf16x8*>(&qb[sb + (size_t)qrow * HD_ + qc8 * 8]);
      qr1 = *reinterpret_cast<const bf16x8*>(&qb[sb + (size_t)(qrow + 32) * HD_ + qc8 * 8]);
      vr0 = *reinterpret_cast<const bf16x8*>(&vb[sb + (size_t)vss * HD_ + vd0]);
      vr1 = *reinterpret_cast<const bf16x8*>(&vb[sb + (size_t)vss * HD_ + vd0 + 32]);
    }
    __builtin_amdgcn_sched_barrier(0);

    f32x4 sf[4];
#pragma unroll
    for (int cf = 0; cf < 4; ++cf) sf[cf] = {0.f, 0.f, 0.f, 0.f};
    __builtin_amdgcn_s_setprio(1);
#pragma unroll
    for (int ks = 0; ks < 2; ++ks) {
#pragma unroll
      for (int cf = 0; cf < 4; ++cf) {
        bf16x8 bq = *reinterpret_cast<const bf16x8*>(&q_lds[buf][(cf * 16 + l15) * 72 + ks * 32 + lh * 8]);
        sf[cf] = __builtin_amdgcn_mfma_f32_16x16x32_bf16(kf[ks], bq, sf[cf], 0, 0, 0);
      }
    }
    __builtin_amdgcn_s_setprio(0);

    const bool diag = (j == jt);
    const int s0 = j * 64;
    float pv[4][4];
#pragma unroll
    for (int r = 0; r < 4; ++r) {
      const int tg = t0 + w * 16 + lh * 4 + r;
      float pm = -1e30f;
#pragma unroll
      for (int cf = 0; cf < 4; ++cf) {
        float v = sf[cf][r];
        if (diag && (s0 + cf * 16 + l15) > tg) v = -1e30f;
        pv[cf][r] = v;
        pm = fmaxf(pm, v);
      }
      pm = fmaxf(pm, __shfl_xor(pm, 1));
      pm = fmaxf(pm, __shfl_xor(pm, 2));
      pm = fmaxf(pm, __shfl_xor(pm, 4));
      pm = fmaxf(pm, __shfl_xor(pm, 8));
      float mn = fmaxf(mrun[r], pm);
      float scl = exp2f(mrun[r] - mn);
      mrun[r] = mn;
      float rs = 0.f;
#pragma unroll
      for (int cf = 0; cf < 4; ++cf) {
        float e = exp2f(pv[cf][r] - mn);
        pv[cf][r] = e;
        rs += e;
      }
      rs += __shfl_xor(rs, 1);
      rs += __shfl_xor(rs, 2);
      rs += __shfl_xor(rs, 4);
      rs += __shfl_xor(rs, 8);
      lrun[r] = lrun[r] * scl + rs;
#pragma unroll
      for (int df = 0; df < 4; ++df) o[df][r] *= scl;
    }
#pragma unroll
    for (int cf = 0; cf < 4; ++cf)
#pragma unroll
      for (int r = 0; r < 4; ++r)
        p_lds[(w * 16 + lh * 4 + r) * 72 + cf * 16 + l15] = f2bf(pv[cf][r]);

    __builtin_amdgcn_s_setprio(1);
#pragma unroll
    for (int ks = 0; ks < 2; ++ks) {
      bf16x8 pa = *reinterpret_cast<const bf16x8*>(&p_lds[(w * 16 + l15) * 72 + ks * 32 + lh * 8]);
#pragma unroll
      for (int df = 0; df < 4; ++df) {
        bf16x8 bv = *reinterpret_cast<const bf16x8*>(&v_lds[buf][(df * 16 + l15) * 72 + ks * 32 + lh * 8]);
        o[df] = __builtin_amdgcn_mfma_f32_16x16x32_bf16(pa, bv, o[df], 0, 0, 0);
      }
    }
    __builtin_amdgcn_s_setprio(0);
  }

#pragma unroll
  for (int r = 0; r < 4; ++r) {
    float inv = 1.f / lrun[r];
    int row = t0 + w * 16 + lh * 4 + r;
#pragma unroll
    for (int df = 0; df < 4; ++df)
      out[base + (size_t)row * HD_ + df * 16 + l15] = o[df][r] * inv;
  }
}

extern "C" void kernel_launch(void* const* d_in, const int* in_sizes, int n_in,
                              void* d_out, int out_size, void* d_ws, size_t ws_size,
                              hipStream_t stream) {
  const float* x  = (const float*)d_in[0];
  const float* Wk = (const float*)d_in[1];
  const float* Wq = (const float*)d_in[2];
  const float* Wv = (const float*)d_in[3];
  float* out = (float*)d_out;

  char* ws = (char*)d_ws;
  unsigned short* w3 = (unsigned short*)ws;                                  // 384 KB
  unsigned short* kb = (unsigned short*)(ws + 524288);                       // 4 MB
  unsigned short* qb = (unsigned short*)(ws + 524288 + 4 * 1024 * 1024);     // 4 MB
  unsigned short* vb = (unsigned short*)(ws + 524288 + 8 * 1024 * 1024);     // 4 MB

  hipLaunchKernelGGL(wconv_kernel, dim3(768), dim3(256), 0, stream, Wk, Wq, Wv, w3);
  hipLaunchKernelGGL(qkv_kernel, dim3(1024), dim3(256), 0, stream, x, w3, kb, qb, vb);
  hipLaunchKernelGGL(attn_kernel, dim3(512), dim3(256), 0, stream, kb, qb, vb, out);
}